// Round 5
// baseline (377.800 us; speedup 1.0000x reference)
//
#include <hip/hip_runtime.h>
#include <hip/hip_bf16.h>

typedef __attribute__((ext_vector_type(8))) __bf16 bf16x8;
typedef __attribute__((ext_vector_type(4))) __bf16 bf16x4;
typedef __attribute__((ext_vector_type(4))) float f32x4;

// qkv: (3, 4, 4096, 256) fp32; conv_w: (256,1,3,3) fp32; conv_b: (256,) fp32
// windows: H_SP=64 (rows), W_SP=8 (cols) -> 8 col-strips per image, WIN=512
// out = [ x: (4,4096,256) | attn: (32,8,512,512) ]  (fp32)
// 512-thread blocks (8 waves = 2 waves/SIMD), grid 256 (one per window-head).
// R3 structure (best measured). sP holds NORMALIZED P (bf16, e*inv folded at
// pack) -> attn readback is pure b128-read + cvt + contiguous 1KB NT store;
// PV output comes out pre-normalized (epilogue drops the inv mul).

#define S2F 0.2550633201964024f   // (1/sqrt(32)) * log2(e)

__global__ __launch_bounds__(512, 2)
void lepe_attn(const float* __restrict__ qkv,
               const float* __restrict__ conv_w,
               const float* __restrict__ conv_b,
               float* __restrict__ out)
{
    constexpr int kL = 4096, kC = 256, kHD = 32;
    constexpr int KSTR = 40;    // 20 dwords/row  -> conflict-free b128 reads
    constexpr int VSTR = 520;   // 260 dwords == 4 (mod 32) -> conflict-free
    constexpr int PSTR = 264;   // 132 dwords == 4 (mod 32) -> conflict-free

    __shared__ __align__(16) __bf16 sK [512 * KSTR];     // 40960 B : K  [t][d]
    __shared__ __align__(16) __bf16 sVt[ 32 * VSTR];     // 33280 B : V^T [d][t]
    __shared__ __align__(16) __bf16 sP [8 * 16 * PSTR];  // 67584 B : per-wave P [16][264]

    const int bx = blockIdx.x;        // 0..255  == wb*8 + h
    const int wb = bx >> 3;
    const int h  = bx & 7;
    const int b  = wb >> 3;           // batch
    const int w  = wb & 7;            // column strip
    const int tid  = threadIdx.x;
    const int lane = tid & 63;
    const int wave = tid >> 6;        // 0..7
    const int l15  = lane & 15;
    const int quad = lane >> 4;

    const float* kBase = qkv + (size_t)4 * kL * kC;       // k slab
    const float* vBase = qkv + (size_t)8 * kL * kC;       // v slab

    // ---- stage K (bf16 row-major) and V^T (bf16) into LDS ----
    #pragma unroll
    for (int chunk = 0; chunk < 4; ++chunk) {
        int e  = chunk * 4096 + tid * 8;          // element in [0,16384)
        int t  = e >> 5;                          // window token 0..511
        int d0 = e & 31;                          // head-channel chunk {0,8,16,24}
        int l  = ((t >> 3) << 6) + (w << 3) + (t & 7);   // token in image
        size_t g = ((size_t)(b * kL + l)) * kC + h * kHD + d0;
        f32x4 k0 = *(const f32x4*)(kBase + g);
        f32x4 k1 = *(const f32x4*)(kBase + g + 4);
        bf16x8 kk;
        kk[0] = (__bf16)k0[0]; kk[1] = (__bf16)k0[1];
        kk[2] = (__bf16)k0[2]; kk[3] = (__bf16)k0[3];
        kk[4] = (__bf16)k1[0]; kk[5] = (__bf16)k1[1];
        kk[6] = (__bf16)k1[2]; kk[7] = (__bf16)k1[3];
        *(bf16x8*)&sK[t * KSTR + d0] = kk;
        f32x4 v0 = *(const f32x4*)(vBase + g);
        f32x4 v1 = *(const f32x4*)(vBase + g + 4);
        sVt[(d0 + 0) * VSTR + t] = (__bf16)v0[0];
        sVt[(d0 + 1) * VSTR + t] = (__bf16)v0[1];
        sVt[(d0 + 2) * VSTR + t] = (__bf16)v0[2];
        sVt[(d0 + 3) * VSTR + t] = (__bf16)v0[3];
        sVt[(d0 + 4) * VSTR + t] = (__bf16)v1[0];
        sVt[(d0 + 5) * VSTR + t] = (__bf16)v1[1];
        sVt[(d0 + 6) * VSTR + t] = (__bf16)v1[2];
        sVt[(d0 + 7) * VSTR + t] = (__bf16)v1[3];
    }

    // ---- LePE conv weights for this thread's 2 channels (fp32) ----
    float w9[2][9], wbias[2];
    #pragma unroll
    for (int nt = 0; nt < 2; ++nt) {
        int c = h * kHD + nt * 16 + l15;
        #pragma unroll
        for (int k = 0; k < 9; ++k) w9[nt][k] = conv_w[c * 9 + k];
        wbias[nt] = conv_b[c];
    }

    __syncthreads();

    float* attnOut = out + (size_t)4 * kL * kC;
    __bf16* sPw = &sP[wave * 16 * PSTR];

    for (int qt = 0; qt < 4; ++qt) {
        const int qrow0 = qt * 128 + wave * 16;   // this wave's 16 q rows

        // A fragment: Q[qrow0 + l15][quad*8 .. +7] from global, fp32 -> bf16
        int tq = qrow0 + l15;
        int lq = ((tq >> 3) << 6) + (w << 3) + (tq & 7);
        const float* qp = qkv + ((size_t)(b * kL + lq)) * kC + h * kHD + quad * 8;
        f32x4 q0 = *(const f32x4*)qp;
        f32x4 q1 = *(const f32x4*)(qp + 4);
        bf16x8 a_frag;
        a_frag[0] = (__bf16)q0[0]; a_frag[1] = (__bf16)q0[1];
        a_frag[2] = (__bf16)q0[2]; a_frag[3] = (__bf16)q0[3];
        a_frag[4] = (__bf16)q1[0]; a_frag[5] = (__bf16)q1[1];
        a_frag[6] = (__bf16)q1[2]; a_frag[7] = (__bf16)q1[3];

        // ---- S = Q K^T  (one MFMA per 16x16 tile, K-dim = hd = 32) ----
        f32x4 accS[32];
        const f32x4 zf = {0.f, 0.f, 0.f, 0.f};
        #pragma unroll
        for (int nt = 0; nt < 32; ++nt) {
            bf16x8 b_frag = *(const bf16x8*)&sK[(nt * 16 + l15) * KSTR + quad * 8];
            accS[nt] = __builtin_amdgcn_mfma_f32_16x16x32_bf16(a_frag, b_frag, zf, 0, 0, 0);
        }

        // ---- softmax over 512 cols (row r lives in the 16 lanes of a quad) ----
        float mr[4] = {-3.0e38f, -3.0e38f, -3.0e38f, -3.0e38f};
        #pragma unroll
        for (int nt = 0; nt < 32; ++nt) {
            #pragma unroll
            for (int r = 0; r < 4; ++r) {
                float sv = accS[nt][r] * S2F;     // scale folded with log2(e)
                accS[nt][r] = sv;
                mr[r] = fmaxf(mr[r], sv);
            }
        }
        #pragma unroll
        for (int r = 0; r < 4; ++r) {
            mr[r] = fmaxf(mr[r], __shfl_xor(mr[r], 1));
            mr[r] = fmaxf(mr[r], __shfl_xor(mr[r], 2));
            mr[r] = fmaxf(mr[r], __shfl_xor(mr[r], 4));
            mr[r] = fmaxf(mr[r], __shfl_xor(mr[r], 8));
        }
        float sr[4] = {0.f, 0.f, 0.f, 0.f};
        #pragma unroll
        for (int nt = 0; nt < 32; ++nt) {
            #pragma unroll
            for (int r = 0; r < 4; ++r) {
                float e = exp2f(accS[nt][r] - mr[r]);   // v_exp_f32 directly
                accS[nt][r] = e;
                sr[r] += e;
            }
        }
        float inv[4];
        #pragma unroll
        for (int r = 0; r < 4; ++r) {
            sr[r] += __shfl_xor(sr[r], 1);
            sr[r] += __shfl_xor(sr[r], 2);
            sr[r] += __shfl_xor(sr[r], 4);
            sr[r] += __shfl_xor(sr[r], 8);
            inv[r] = 1.0f / sr[r];
        }

        const size_t qBase = (size_t)bx * (512 * 512) + (size_t)qrow0 * 512;

        // ---- two half-passes over the 512 cols ----
        f32x4 accO0 = zf, accO1 = zf;
        #pragma unroll
        for (int half = 0; half < 2; ++half) {
            // pack NORMALIZED p = e*inv -> sP (bf16) [16 rows][256 cols of this half]
            #pragma unroll
            for (int nt = 0; nt < 16; ++nt) {
                #pragma unroll
                for (int r = 0; r < 4; ++r)
                    sPw[(quad * 4 + r) * PSTR + nt * 16 + l15] =
                        (__bf16)(accS[half * 16 + nt][r] * inv[r]);
            }

            // attn stores: b128 readback, 2 rows/iter (32 lanes each = 1KB
            // fully-contiguous NT store per row-half)
            #pragma unroll
            for (int rr = 0; rr < 8; ++rr) {
                int row = rr * 2 + (lane >> 5);
                int cb  = (lane & 31) * 8;
                bf16x8 ev = *(const bf16x8*)&sPw[row * PSTR + cb];
                f32x4 o0, o1;
                o0[0] = (float)ev[0]; o0[1] = (float)ev[1];
                o0[2] = (float)ev[2]; o0[3] = (float)ev[3];
                o1[0] = (float)ev[4]; o1[1] = (float)ev[5];
                o1[2] = (float)ev[6]; o1[3] = (float)ev[7];
                float* dst = attnOut + qBase + (size_t)row * 512 + half * 256 + cb;
                __builtin_nontemporal_store(o0, (f32x4*)dst);
                __builtin_nontemporal_store(o1, (f32x4*)(dst + 4));
            }

            // ---- O += P V  (A = P rows from sP, B = V^T rows) ----
            #pragma unroll
            for (int c = 0; c < 8; ++c) {
                bf16x8 pa  = *(const bf16x8*)&sPw[l15 * PSTR + c * 32 + quad * 8];
                bf16x8 vb0 = *(const bf16x8*)&sVt[ l15        * VSTR + half * 256 + c * 32 + quad * 8];
                bf16x8 vb1 = *(const bf16x8*)&sVt[(16 + l15) * VSTR + half * 256 + c * 32 + quad * 8];
                accO0 = __builtin_amdgcn_mfma_f32_16x16x32_bf16(pa, vb0, accO0, 0, 0, 0);
                accO1 = __builtin_amdgcn_mfma_f32_16x16x32_bf16(pa, vb1, accO1, 0, 0, 0);
            }
        }

        // ---- epilogue: accO (already normalized) + LePE 3x3 depthwise ----
        const int t0  = qrow0 + quad * 4;       // 4 consecutive tokens, same image row
        const int r0  = t0 >> 3;
        const int cw0 = t0 & 7;                 // 0 or 4
        #pragma unroll
        for (int nt = 0; nt < 2; ++nt) {
            const int dch = nt * 16 + l15;
            float patch[3][6];
            #pragma unroll
            for (int i = 0; i < 3; ++i) {
                int r2 = r0 - 1 + i;
                #pragma unroll
                for (int j = 0; j < 6; ++j) {
                    int c2 = cw0 - 1 + j;
                    bool ok = (r2 >= 0) && (r2 < 64) && (c2 >= 0) && (c2 < 8);
                    patch[i][j] = ok ? (float)sVt[dch * VSTR + r2 * 8 + c2] : 0.0f;
                }
            }
            #pragma unroll
            for (int r = 0; r < 4; ++r) {
                float acc = (nt ? accO1[r] : accO0[r]) + wbias[nt];
                #pragma unroll
                for (int i = 0; i < 3; ++i)
                    #pragma unroll
                    for (int jj = 0; jj < 3; ++jj)
                        acc += w9[nt][i * 3 + jj] * patch[i][r + jj];
                int trow = t0 + r;
                int lo = ((trow >> 3) << 6) + (w << 3) + (trow & 7);
                __builtin_nontemporal_store(
                    acc, out + ((size_t)(b * kL + lo)) * kC + h * kHD + dch);
            }
        }
    }
}

extern "C" void kernel_launch(void* const* d_in, const int* in_sizes, int n_in,
                              void* d_out, int out_size, void* d_ws, size_t ws_size,
                              hipStream_t stream) {
    const float* qkv = (const float*)d_in[0];
    const float* cw  = (const float*)d_in[1];
    const float* cb  = (const float*)d_in[2];
    float* outp = (float*)d_out;
    lepe_attn<<<dim3(256), dim3(512), 0, stream>>>(qkv, cw, cb, outp);
}

// Round 6
// 324.740 us; speedup vs baseline: 1.1634x; 1.1634x over previous
//
#include <hip/hip_runtime.h>
#include <hip/hip_bf16.h>

typedef __attribute__((ext_vector_type(8))) __bf16 bf16x8;
typedef __attribute__((ext_vector_type(4))) __bf16 bf16x4;
typedef __attribute__((ext_vector_type(4))) float f32x4;

// qkv: (3, 4, 4096, 256) fp32; conv_w: (256,1,3,3) fp32; conv_b: (256,) fp32
// windows: H_SP=64 (rows), W_SP=8 (cols) -> 8 col-strips per image, WIN=512
// out = [ x: (4,4096,256) | attn: (32,8,512,512) ]  (fp32)
// 512-thread blocks (8 waves = 2 waves/SIMD), grid 256 (one per window-head).
// R3 structure (best measured: 326.8us). sP holds UNNORMALIZED exp2 (bf16) so
// the pack depends only on exp, overlapping the sum-reduce; normalize at
// readback; contiguous 1KB NT stores. R6 adds: next-qt Q global prefetch
// issued right after QK^T (hides HBM/L2 latency under softmax+PV), and invR
// broadcasts hoisted out of the half-loop.

#define S2F 0.2550633201964024f   // (1/sqrt(32)) * log2(e)

__global__ __launch_bounds__(512, 2)
void lepe_attn(const float* __restrict__ qkv,
               const float* __restrict__ conv_w,
               const float* __restrict__ conv_b,
               float* __restrict__ out)
{
    constexpr int kL = 4096, kC = 256, kHD = 32;
    constexpr int KSTR = 40;    // 20 dwords/row  -> conflict-free b128 reads
    constexpr int VSTR = 520;   // 260 dwords == 4 (mod 32) -> conflict-free
    constexpr int PSTR = 264;   // 132 dwords == 4 (mod 32) -> conflict-free

    __shared__ __align__(16) __bf16 sK [512 * KSTR];     // 40960 B : K  [t][d]
    __shared__ __align__(16) __bf16 sVt[ 32 * VSTR];     // 33280 B : V^T [d][t]
    __shared__ __align__(16) __bf16 sP [8 * 16 * PSTR];  // 67584 B : per-wave e [16][264]

    const int bx = blockIdx.x;        // 0..255  == wb*8 + h
    const int wb = bx >> 3;
    const int h  = bx & 7;
    const int b  = wb >> 3;           // batch
    const int w  = wb & 7;            // column strip
    const int tid  = threadIdx.x;
    const int lane = tid & 63;
    const int wave = tid >> 6;        // 0..7
    const int l15  = lane & 15;
    const int quad = lane >> 4;

    const float* kBase = qkv + (size_t)4 * kL * kC;       // k slab
    const float* vBase = qkv + (size_t)8 * kL * kC;       // v slab

    // ---- stage K (bf16 row-major) and V^T (bf16) into LDS ----
    #pragma unroll
    for (int chunk = 0; chunk < 4; ++chunk) {
        int e  = chunk * 4096 + tid * 8;          // element in [0,16384)
        int t  = e >> 5;                          // window token 0..511
        int d0 = e & 31;                          // head-channel chunk {0,8,16,24}
        int l  = ((t >> 3) << 6) + (w << 3) + (t & 7);   // token in image
        size_t g = ((size_t)(b * kL + l)) * kC + h * kHD + d0;
        f32x4 k0 = *(const f32x4*)(kBase + g);
        f32x4 k1 = *(const f32x4*)(kBase + g + 4);
        bf16x8 kk;
        kk[0] = (__bf16)k0[0]; kk[1] = (__bf16)k0[1];
        kk[2] = (__bf16)k0[2]; kk[3] = (__bf16)k0[3];
        kk[4] = (__bf16)k1[0]; kk[5] = (__bf16)k1[1];
        kk[6] = (__bf16)k1[2]; kk[7] = (__bf16)k1[3];
        *(bf16x8*)&sK[t * KSTR + d0] = kk;
        f32x4 v0 = *(const f32x4*)(vBase + g);
        f32x4 v1 = *(const f32x4*)(vBase + g + 4);
        sVt[(d0 + 0) * VSTR + t] = (__bf16)v0[0];
        sVt[(d0 + 1) * VSTR + t] = (__bf16)v0[1];
        sVt[(d0 + 2) * VSTR + t] = (__bf16)v0[2];
        sVt[(d0 + 3) * VSTR + t] = (__bf16)v0[3];
        sVt[(d0 + 4) * VSTR + t] = (__bf16)v1[0];
        sVt[(d0 + 5) * VSTR + t] = (__bf16)v1[1];
        sVt[(d0 + 6) * VSTR + t] = (__bf16)v1[2];
        sVt[(d0 + 7) * VSTR + t] = (__bf16)v1[3];
    }

    // ---- LePE conv weights for this thread's 2 channels (fp32) ----
    float w9[2][9], wbias[2];
    #pragma unroll
    for (int nt = 0; nt < 2; ++nt) {
        int c = h * kHD + nt * 16 + l15;
        #pragma unroll
        for (int k = 0; k < 9; ++k) w9[nt][k] = conv_w[c * 9 + k];
        wbias[nt] = conv_b[c];
    }

    __syncthreads();

    float* attnOut = out + (size_t)4 * kL * kC;
    __bf16* sPw = &sP[wave * 16 * PSTR];

    // ---- prologue: load Q for qt=0 ----
    auto qAddr = [&](int qt_) {
        int tq = qt_ * 128 + wave * 16 + l15;
        int lq = ((tq >> 3) << 6) + (w << 3) + (tq & 7);
        return qkv + ((size_t)(b * kL + lq)) * kC + h * kHD + quad * 8;
    };
    f32x4 q0 = *(const f32x4*)qAddr(0);
    f32x4 q1 = *(const f32x4*)(qAddr(0) + 4);

    for (int qt = 0; qt < 4; ++qt) {
        const int qrow0 = qt * 128 + wave * 16;   // this wave's 16 q rows

        // A fragment from the prefetched Q registers, fp32 -> bf16
        bf16x8 a_frag;
        a_frag[0] = (__bf16)q0[0]; a_frag[1] = (__bf16)q0[1];
        a_frag[2] = (__bf16)q0[2]; a_frag[3] = (__bf16)q0[3];
        a_frag[4] = (__bf16)q1[0]; a_frag[5] = (__bf16)q1[1];
        a_frag[6] = (__bf16)q1[2]; a_frag[7] = (__bf16)q1[3];

        // ---- S = Q K^T  (one MFMA per 16x16 tile, K-dim = hd = 32) ----
        f32x4 accS[32];
        const f32x4 zf = {0.f, 0.f, 0.f, 0.f};
        #pragma unroll
        for (int nt = 0; nt < 32; ++nt) {
            bf16x8 b_frag = *(const bf16x8*)&sK[(nt * 16 + l15) * KSTR + quad * 8];
            accS[nt] = __builtin_amdgcn_mfma_f32_16x16x32_bf16(a_frag, b_frag, zf, 0, 0, 0);
        }

        // ---- prefetch next qt's Q now: latency hides under softmax+PV ----
        if (qt < 3) {
            const float* qp = qAddr(qt + 1);
            q0 = *(const f32x4*)qp;
            q1 = *(const f32x4*)(qp + 4);
        }

        // ---- softmax over 512 cols (row r lives in the 16 lanes of a quad) ----
        float mr[4] = {-3.0e38f, -3.0e38f, -3.0e38f, -3.0e38f};
        #pragma unroll
        for (int nt = 0; nt < 32; ++nt) {
            #pragma unroll
            for (int r = 0; r < 4; ++r) {
                float sv = accS[nt][r] * S2F;     // scale folded with log2(e)
                accS[nt][r] = sv;
                mr[r] = fmaxf(mr[r], sv);
            }
        }
        #pragma unroll
        for (int r = 0; r < 4; ++r) {
            mr[r] = fmaxf(mr[r], __shfl_xor(mr[r], 1));
            mr[r] = fmaxf(mr[r], __shfl_xor(mr[r], 2));
            mr[r] = fmaxf(mr[r], __shfl_xor(mr[r], 4));
            mr[r] = fmaxf(mr[r], __shfl_xor(mr[r], 8));
        }
        float sr[4] = {0.f, 0.f, 0.f, 0.f};
        #pragma unroll
        for (int nt = 0; nt < 32; ++nt) {
            #pragma unroll
            for (int r = 0; r < 4; ++r) {
                float e = exp2f(accS[nt][r] - mr[r]);   // v_exp_f32 directly
                accS[nt][r] = e;
                sr[r] += e;
            }
        }
        float inv[4];
        #pragma unroll
        for (int r = 0; r < 4; ++r) {
            sr[r] += __shfl_xor(sr[r], 1);
            sr[r] += __shfl_xor(sr[r], 2);
            sr[r] += __shfl_xor(sr[r], 4);
            sr[r] += __shfl_xor(sr[r], 8);
            inv[r] = 1.0f / sr[r];
        }

        // per-row inv broadcasts, hoisted (constant-indexed -> registers)
        float invRow[16];
        #pragma unroll
        for (int r = 0; r < 16; ++r)
            invRow[r] = __shfl(inv[r & 3], (r >> 2) * 16);

        const size_t qBase = (size_t)bx * (512 * 512) + (size_t)qrow0 * 512;

        // ---- two half-passes over the 512 cols ----
        f32x4 accO0 = zf, accO1 = zf;
        #pragma unroll
        for (int half = 0; half < 2; ++half) {
            // e -> sP (bf16) [16 rows][256 cols of this half]; dep: exp only,
            // co-schedules under the sum-reduce shuffles above
            #pragma unroll
            for (int nt = 0; nt < 16; ++nt) {
                #pragma unroll
                for (int r = 0; r < 4; ++r)
                    sPw[(quad * 4 + r) * PSTR + nt * 16 + l15] =
                        (__bf16)accS[half * 16 + nt][r];
            }

            // attn stores: one fully-contiguous 1KB nontemporal store per row
            // (64 lanes x 16B = 8 complete 128B lines; stream past L2)
            #pragma unroll
            for (int r = 0; r < 16; ++r) {
                bf16x4 ev = *(const bf16x4*)&sPw[r * PSTR + lane * 4];
                f32x4 o;
                o[0] = (float)ev[0] * invRow[r];
                o[1] = (float)ev[1] * invRow[r];
                o[2] = (float)ev[2] * invRow[r];
                o[3] = (float)ev[3] * invRow[r];
                __builtin_nontemporal_store(
                    o, (f32x4*)(attnOut + qBase + (size_t)r * 512 + half * 256 + lane * 4));
            }

            // ---- O += P V  (A = P rows from sP, B = V^T rows) ----
            #pragma unroll
            for (int c = 0; c < 8; ++c) {
                bf16x8 pa  = *(const bf16x8*)&sPw[l15 * PSTR + c * 32 + quad * 8];
                bf16x8 vb0 = *(const bf16x8*)&sVt[ l15        * VSTR + half * 256 + c * 32 + quad * 8];
                bf16x8 vb1 = *(const bf16x8*)&sVt[(16 + l15) * VSTR + half * 256 + c * 32 + quad * 8];
                accO0 = __builtin_amdgcn_mfma_f32_16x16x32_bf16(pa, vb0, accO0, 0, 0, 0);
                accO1 = __builtin_amdgcn_mfma_f32_16x16x32_bf16(pa, vb1, accO1, 0, 0, 0);
            }
        }

        // ---- epilogue: accO*inv + LePE (3x3 depthwise over V^T image in LDS) ----
        const int t0  = qrow0 + quad * 4;       // 4 consecutive tokens, same image row
        const int r0  = t0 >> 3;
        const int cw0 = t0 & 7;                 // 0 or 4
        #pragma unroll
        for (int nt = 0; nt < 2; ++nt) {
            const int dch = nt * 16 + l15;
            float patch[3][6];
            #pragma unroll
            for (int i = 0; i < 3; ++i) {
                int r2 = r0 - 1 + i;
                #pragma unroll
                for (int j = 0; j < 6; ++j) {
                    int c2 = cw0 - 1 + j;
                    bool ok = (r2 >= 0) && (r2 < 64) && (c2 >= 0) && (c2 < 8);
                    patch[i][j] = ok ? (float)sVt[dch * VSTR + r2 * 8 + c2] : 0.0f;
                }
            }
            #pragma unroll
            for (int r = 0; r < 4; ++r) {
                float acc = (nt ? accO1[r] : accO0[r]) * inv[r] + wbias[nt];
                #pragma unroll
                for (int i = 0; i < 3; ++i)
                    #pragma unroll
                    for (int jj = 0; jj < 3; ++jj)
                        acc += w9[nt][i * 3 + jj] * patch[i][r + jj];
                int trow = t0 + r;
                int lo = ((trow >> 3) << 6) + (w << 3) + (trow & 7);
                __builtin_nontemporal_store(
                    acc, out + ((size_t)(b * kL + lo)) * kC + h * kHD + dch);
            }
        }
    }
}

extern "C" void kernel_launch(void* const* d_in, const int* in_sizes, int n_in,
                              void* d_out, int out_size, void* d_ws, size_t ws_size,
                              hipStream_t stream) {
    const float* qkv = (const float*)d_in[0];
    const float* cw  = (const float*)d_in[1];
    const float* cb  = (const float*)d_in[2];
    float* outp = (float*)d_out;
    lepe_attn<<<dim3(256), dim3(512), 0, stream>>>(qkv, cw, cb, outp);
}